// Round 13
// baseline (277.220 us; speedup 1.0000x reference)
//
#include <hip/hip_runtime.h>
#include <hip/hip_bf16.h>

#define BATCH 16384
#define INF 768
#define OUTF 768
#define NSLAB 9                  // slab order per ib: {8=silu, 0..7=rbf}
#define KTOT (NSLAB * INF)       // 6912
#define BM 128
#define BN 192                   // grid = 128*4 = 512 = 2/CU * 256CU, 1 clean gen
#define BK 64
#define KB_TILES 12              // INF / BK
#define NTILES (NSLAB * KB_TILES)
#define NRB (BATCH / BM)         // 128 row blocks
#define NCB (OUTF / BN)          // 4 col blocks

#define LOG2E 1.4426950408889634f
#define EXPM2 0.13533528323661270f   // exp(-2)

// tiled-B layout (shorts): tile(cb,kt) = 24 KB contiguous, kt = slab*12 + ib
#define TILE_SH (BN * BK)              // 12288 shorts = 24 KB
#define IB_SH   TILE_SH
#define SLAB_SH (KB_TILES * TILE_SH)
#define CB_SH   ((size_t)NTILES * TILE_SH)

typedef __bf16 bf16x8 __attribute__((ext_vector_type(8)));
typedef float f32x4 __attribute__((ext_vector_type(4)));
typedef unsigned short ushort8v __attribute__((ext_vector_type(8)));

__device__ __forceinline__ unsigned short f2bf(float f) {
  unsigned u = __builtin_bit_cast(unsigned, f);
  u += 0x7fffu + ((u >> 16) & 1u);     // RTNE
  return (unsigned short)(u >> 16);
}

__device__ __forceinline__ unsigned cvt2(float a, float b) {
  unsigned r;
  asm("v_cvt_pk_bf16_f32 %0, %1, %2" : "=v"(r) : "v"(a), "v"(b));
  return r;
}

__device__ __forceinline__ bf16x8 pack8(const f32x4 a, const f32x4 b) {
  union { uint4 u; bf16x8 v; } r;
  r.u.x = cvt2(a[0], a[1]); r.u.y = cvt2(a[2], a[3]);
  r.u.z = cvt2(b[0], b[1]); r.u.w = cvt2(b[2], b[3]);
  return r.v;
}

__device__ __forceinline__ void gload_lds16(const void* g, void* l) {
  __builtin_amdgcn_global_load_lds(
      (const __attribute__((address_space(1))) unsigned int*)g,
      (__attribute__((address_space(3))) unsigned int*)l, 16, 0, 0);
}

// ---- kernel 1: build W_ext pre-tiled for 192-col staging ---------------------
// 16B-group index gid within bext3 maps exactly to the GEMM stage order:
// tile = gid/1536 (24KB tiles), g = gid%1536, q = g>>8, t = g&255,
// row = q*32 + (t>>3), ch = t&7; kt = tile%108 -> a = kt/12, ib = kt%12;
// o = cb*192 + row; i = ib*64 + (ch ^ (row&7))*8   (chunk pre-XOR-swizzled).
__global__ __launch_bounds__(256) void build_bext3(
    const float* __restrict__ w_b, const float* __restrict__ w_s,
    const float* __restrict__ c, unsigned short* __restrict__ bt) {
  const int gid = blockIdx.x * 256 + threadIdx.x;
  const int tile = gid / 1536;
  const int g = gid - tile * 1536;
  const int q = g >> 8;
  const int tt = g & 255;
  const int row = q * 32 + (tt >> 3);
  const int ch = tt & 7;
  const int cbq = tile / NTILES;
  const int kt = tile - cbq * NTILES;
  const int a = kt / KB_TILES;
  const int ib = kt - a * KB_TILES;
  const int o = cbq * BN + row;
  const int i = ib * 64 + (ch ^ (row & 7)) * 8;

  float4 v0, v1;
  if (a < 8) {
    const float* cp = c + ((size_t)(a * OUTF + o)) * INF + i;
    const float* wp = w_s + (size_t)o * INF + i;
    const float4 c0 = *(const float4*)cp, c1 = *(const float4*)(cp + 4);
    const float4 s0 = *(const float4*)wp, s1 = *(const float4*)(wp + 4);
    v0 = make_float4(c0.x * s0.x, c0.y * s0.y, c0.z * s0.z, c0.w * s0.w);
    v1 = make_float4(c1.x * s1.x, c1.y * s1.y, c1.z * s1.z, c1.w * s1.w);
  } else {
    const float* bp = w_b + (size_t)o * INF + i;
    v0 = *(const float4*)bp;
    v1 = *(const float4*)(bp + 4);
  }
  ushort8v r;
  r[0] = f2bf(v0.x); r[1] = f2bf(v0.y); r[2] = f2bf(v0.z); r[3] = f2bf(v0.w);
  r[4] = f2bf(v1.x); r[5] = f2bf(v1.y); r[6] = f2bf(v1.z); r[7] = f2bf(v1.w);
  *(ushort8v*)(bt + (size_t)gid * 8) = r;
}

// ---- kernel 2: BN=192, 512 blocks (one clean generation), ring-3 LDS,
//      9-stage unroll, A in regs + A-fragment pipeline (round-12 proven). -----
__global__ __launch_bounds__(256, 2) void kan_gemm10(
    const float* __restrict__ x, const unsigned short* __restrict__ bt,
    float* __restrict__ out) {
  __shared__ unsigned short Bs[3][TILE_SH];   // 3 x 24 KiB ring

  const int orig = blockIdx.x;
  const int bid = (orig & 7) * 64 + (orig >> 3);   // bijective XCD swizzle (512=8*64)
  const int cb = bid / NRB;                        // cb-major: XCD chunk shares B-strip
  const int rb = bid - cb * NRB;
  const int row0 = rb * BM, col0 = cb * BN;

  const int t = threadIdx.x;
  const int lane = t & 63;
  const int w = t >> 6;                            // wave w: rows w*32..+31, all 192 cols
  const int lrow = lane & 15, lhi = lane >> 4;

  f32x4 acc[2][12];
#pragma unroll
  for (int mt = 0; mt < 2; ++mt)
#pragma unroll
    for (int n = 0; n < 12; ++n)
      acc[mt][n] = (f32x4){0.f, 0.f, 0.f, 0.f};

  const unsigned short* gt = bt + (size_t)cb * CB_SH + t * 8;
  const float* xb = x + (size_t)(row0 + w * 32 + lrow) * INF;

  const int c0 = lhi ^ (lrow & 7);
  const int c1 = (4 + lhi) ^ (lrow & 7);
  const unsigned short* pB0 = &Bs[0][lrow * 64 + c0 * 8];
  const unsigned short* pB1 = &Bs[0][lrow * 64 + c1 * 8];

  f32x4 ph[2][2][2], gg[2][2][2];   // [mt][kk][half] recurrence state
  bf16x8 afc[2][2];                 // [kk][mt] A-fragments for the CURRENT iter

  auto stage = [&](const unsigned short* src, int slot) {
#pragma unroll
    for (int q = 0; q < 6; ++q)     // 6 x 4KB slices = 24KB tile
      gload_lds16(src + q * 2048, &Bs[slot][q * 2048 + t * 8]);
  };

  auto mma_kk = [&](int kk, int slot) {
    const unsigned short* pB = kk ? pB1 : pB0;
#pragma unroll
    for (int n = 0; n < 12; ++n) {
      const bf16x8 b = *(const bf16x8*)(pB + slot * TILE_SH + n * 1024);
      acc[0][n] = __builtin_amdgcn_mfma_f32_16x16x32_bf16(afc[kk][0], b, acc[0][n], 0, 0, 0);
      acc[1][n] = __builtin_amdgcn_mfma_f32_16x16x32_bf16(afc[kk][1], b, acc[1][n], 0, 0, 0);
    }
  };

  f32x4 xr[2][2][2];   // [mt][kk][half]
  auto load_x = [&](int ib) {
#pragma unroll
    for (int mt = 0; mt < 2; ++mt)
#pragma unroll
      for (int kk = 0; kk < 2; ++kk) {
        const float* p = xb + ib * BK + mt * 16 * INF + kk * 32 + lhi * 8;
        xr[mt][kk][0] = *(const f32x4*)p;
        xr[mt][kk][1] = *(const f32x4*)(p + 4);
      }
  };
  auto silu_init = [&]() {
#pragma unroll
    for (int kk = 0; kk < 2; ++kk)
#pragma unroll
      for (int mt = 0; mt < 2; ++mt) {
        const f32x4 x0 = xr[mt][kk][0], x1 = xr[mt][kk][1];
        f32x4 s0, s1;
#pragma unroll
        for (int e = 0; e < 4; ++e) {
          s0[e] = x0[e] * __builtin_amdgcn_rcpf(
                      1.f + __builtin_amdgcn_exp2f(x0[e] * (-LOG2E)));
          s1[e] = x1[e] * __builtin_amdgcn_rcpf(
                      1.f + __builtin_amdgcn_exp2f(x1[e] * (-LOG2E)));
        }
        afc[kk][mt] = pack8(s0, s1);
        const f32x4 z0 = x0 * 1.75f + 3.5f;   // (x - g0)/h
        const f32x4 z1 = x1 * 1.75f + 3.5f;
#pragma unroll
        for (int e = 0; e < 4; ++e) {
          ph[mt][kk][0][e] = __builtin_amdgcn_exp2f(-(z0[e] * z0[e]) * LOG2E);
          ph[mt][kk][1][e] = __builtin_amdgcn_exp2f(-(z1[e] * z1[e]) * LOG2E);
          gg[mt][kk][0][e] = __builtin_amdgcn_exp2f(z0[e] * (2.f * LOG2E) - LOG2E);
          gg[mt][kk][1][e] = __builtin_amdgcn_exp2f(z1[e] * (2.f * LOG2E) - LOG2E);
        }
      }
  };
  auto pack_advance = [&]() {
#pragma unroll
    for (int kk = 0; kk < 2; ++kk)
#pragma unroll
      for (int mt = 0; mt < 2; ++mt) {
        afc[kk][mt] = pack8(ph[mt][kk][0], ph[mt][kk][1]);
        ph[mt][kk][0] *= gg[mt][kk][0];   // phi_{a+1} = phi_a * G_a
        ph[mt][kk][1] *= gg[mt][kk][1];
        gg[mt][kk][0] = gg[mt][kk][0] * EXPM2;
        gg[mt][kk][1] = gg[mt][kk][1] * EXPM2;
      }
  };

  // ---- prologue: x(ib0) first (oldest in FIFO), stages idx0/idx1;
  //      silu_init auto-drains x; vmcnt(6) ensures stage idx0 complete. ------
  load_x(0);
  const unsigned short* gib = gt;
  stage(gib + 8 * SLAB_SH, 0);   // (ib0, idx0 = slab8/silu)
  stage(gib, 1);                 // (ib0, idx1 = slab0)
  silu_init();
  asm volatile("s_waitcnt vmcnt(6)" ::: "memory");
  __builtin_amdgcn_s_barrier();
  __builtin_amdgcn_sched_barrier(0);

#pragma clang loop unroll(disable)
  for (int ib = 0; ib < KB_TILES; ++ib) {
    const bool last = (ib == KB_TILES - 1);
#pragma unroll
    for (int j = 0; j < 9; ++j) {        // iter j consumes idx j (slab j?j-1:8)
      const int slot = j % 3;

      // A) x loads for next ib's silu (before the stage: drained at E, sparing
      //    the newest prefetch)
      if (j == 8 && !last) load_x(ib + 1);

      // B) issue stage idx j+2
      if (j <= 6) {
        stage(gib + (j + 1) * SLAB_SH, (j + 2) % 3);       // (ib, idx j+2)
      } else if (!last) {
        if (j == 7) stage(gib + 8 * SLAB_SH + IB_SH, 0);   // (ib+1, idx0)
        else        stage(gib + IB_SH, 1);                 // (ib+1, idx1)
      }

      // C) MFMAs with the pipelined fragments (no VALU dependency)
      mma_kk(0, slot);
      mma_kk(1, slot);

      // D) build afc for the NEXT iteration (overlaps C on the VALU pipe)
      if (j < 8)       pack_advance();
      else if (!last)  silu_init();

      // E) counted wait: own stage(j+1) complete (FIFO), newest 6 in flight
      if (!last || j < 7) {
        asm volatile("s_waitcnt vmcnt(6)" ::: "memory");
      } else if (j == 7) {
        asm volatile("s_waitcnt vmcnt(0)" ::: "memory");
      }
      if (!(last && j == 8)) {
        __builtin_amdgcn_s_barrier();
        __builtin_amdgcn_sched_barrier(0);
      }
    }
    gib += IB_SH;
  }

  // epilogue: C/D layout col=lane&15, row=(lane>>4)*4+r
#pragma unroll
  for (int mt = 0; mt < 2; ++mt) {
#pragma unroll
    for (int n = 0; n < 12; ++n) {
      const int row = row0 + w * 32 + mt * 16 + lhi * 4;
      const int col = col0 + n * 16 + lrow;
#pragma unroll
      for (int r = 0; r < 4; ++r)
        out[(size_t)(row + r) * OUTF + col] = acc[mt][n][r];
    }
  }
}

// ---------------- fallback if ws too small (round-1 kernel) ------------------
__device__ __forceinline__ float phi_f(float x, float g) {
  float z = (x - g) * 1.75f;
  return __expf(-z * z);
}
__device__ __forceinline__ float silu_f(float x) {
  return x / (1.f + __expf(-x));
}

__global__ __launch_bounds__(256, 2) void kan_gemm_fb(
    const float* __restrict__ x, const float* __restrict__ w_b,
    const float* __restrict__ w_s, const float* __restrict__ c,
    float* __restrict__ out) {
  __shared__ unsigned short As[128][72];
  __shared__ unsigned short Bs[128][72];

  const int bid = blockIdx.x;
  const int cbf = bid % (OUTF / 128);
  const int rbf = bid / (OUTF / 128);
  const int row0 = rbf * 128, col0 = cbf * 128;

  const int t = threadIdx.x;
  const int lane = t & 63;
  const int w = t >> 6;
  const int wr = w >> 1, wc = w & 1;
  const int lrow = lane & 15, lhi = lane >> 4;

  f32x4 acc[4][4];
#pragma unroll
  for (int m = 0; m < 4; ++m)
#pragma unroll
    for (int n = 0; n < 4; ++n)
      acc[m][n] = (f32x4){0.f, 0.f, 0.f, 0.f};

  const int rsub = t >> 4;
  const int k4 = t & 15;

  for (int kt = 0; kt < KTOT / 64; ++kt) {
    const int a = kt / (INF / 64);
    const int i0 = (kt % (INF / 64)) * 64;
    const float ga = -2.f + (float)a * (4.f / 7.f);

#pragma unroll
    for (int p = 0; p < 8; ++p) {
      const int r = p * 16 + rsub;
      const float4 xv = *(const float4*)(x + (size_t)(row0 + r) * INF + i0 + k4 * 4);
      ushort4 av;
      if (a < 8) {
        av.x = f2bf(phi_f(xv.x, ga)); av.y = f2bf(phi_f(xv.y, ga));
        av.z = f2bf(phi_f(xv.z, ga)); av.w = f2bf(phi_f(xv.w, ga));
      } else {
        av.x = f2bf(silu_f(xv.x)); av.y = f2bf(silu_f(xv.y));
        av.z = f2bf(silu_f(xv.z)); av.w = f2bf(silu_f(xv.w));
      }
      *(ushort4*)&As[r][k4 * 4] = av;

      ushort4 bv;
      if (a < 8) {
        const float4 cv = *(const float4*)(c + ((size_t)a * OUTF + col0 + r) * INF + i0 + k4 * 4);
        const float4 wv = *(const float4*)(w_s + (size_t)(col0 + r) * INF + i0 + k4 * 4);
        bv.x = f2bf(cv.x * wv.x); bv.y = f2bf(cv.y * wv.y);
        bv.z = f2bf(cv.z * wv.z); bv.w = f2bf(cv.w * wv.w);
      } else {
        const float4 bbv = *(const float4*)(w_b + (size_t)(col0 + r) * INF + i0 + k4 * 4);
        bv.x = f2bf(bbv.x); bv.y = f2bf(bbv.y);
        bv.z = f2bf(bbv.z); bv.w = f2bf(bbv.w);
      }
      *(ushort4*)&Bs[r][k4 * 4] = bv;
    }
    __syncthreads();

#pragma unroll
    for (int kk = 0; kk < 2; ++kk) {
      bf16x8 af[4], bfr[4];
#pragma unroll
      for (int m = 0; m < 4; ++m)
        af[m] = *(const bf16x8*)&As[wr * 64 + m * 16 + lrow][kk * 32 + lhi * 8];
#pragma unroll
      for (int n = 0; n < 4; ++n)
        bfr[n] = *(const bf16x8*)&Bs[wc * 64 + n * 16 + lrow][kk * 32 + lhi * 8];
#pragma unroll
      for (int m = 0; m < 4; ++m)
#pragma unroll
        for (int n = 0; n < 4; ++n)
          acc[m][n] = __builtin_amdgcn_mfma_f32_16x16x32_bf16(af[m], bfr[n], acc[m][n], 0, 0, 0);
    }
    __syncthreads();
  }

#pragma unroll
  for (int m = 0; m < 4; ++m) {
#pragma unroll
    for (int n = 0; n < 4; ++n) {
      const int row = row0 + wr * 64 + m * 16 + lhi * 4;
      const int col = col0 + wc * 64 + n * 16 + lrow;
#pragma unroll
      for (int r = 0; r < 4; ++r)
        out[(size_t)(row + r) * OUTF + col] = acc[m][n][r];
    }
  }
}

extern "C" void kernel_launch(void* const* d_in, const int* in_sizes, int n_in,
                              void* d_out, int out_size, void* d_ws, size_t ws_size,
                              hipStream_t stream) {
  const float* x   = (const float*)d_in[0];
  const float* w_b = (const float*)d_in[1];
  const float* w_s = (const float*)d_in[2];
  const float* c   = (const float*)d_in[3];
  float* out = (float*)d_out;

  const size_t need = (size_t)OUTF * KTOT * sizeof(unsigned short);  // 10.1 MiB
  if (ws_size >= need) {
    unsigned short* bt = (unsigned short*)d_ws;
    build_bext3<<<(NCB * NTILES * 1536) / 256, 256, 0, stream>>>(w_b, w_s, c, bt);
    kan_gemm10<<<NRB * NCB, 256, 0, stream>>>(x, bt, out);
  } else {
    kan_gemm_fb<<<(BATCH / 128) * (OUTF / 128), 256, 0, stream>>>(x, w_b, w_s, c, out);
  }
}

// Round 14
// 233.764 us; speedup vs baseline: 1.1859x; 1.1859x over previous
//
#include <hip/hip_runtime.h>
#include <hip/hip_bf16.h>

#define BATCH 16384
#define INF 768
#define OUTF 768
#define NSLAB 9                  // slab order per ib: {8=silu, 0..7=rbf}
#define KTOT (NSLAB * INF)       // 6912
#define BM 128
#define BN 128
#define BK 64
#define KB_TILES 12              // INF / BK
#define NTILES (NSLAB * KB_TILES)
#define KH_IBS (KB_TILES / 2)    // 6 ibs per K-half

#define LOG2E 1.4426950408889634f
#define EXPM2 0.13533528323661270f   // exp(-2)

// tiled-B layout (shorts): tile(cb,kt) = 16 KB contiguous, kt = slab*12 + ib
#define TILE_SH 8192
#define IB_SH   8192             // ib stride within (cb): 1 tile
#define SLAB_SH (KB_TILES * TILE_SH)   // slab stride: 12 tiles

typedef __bf16 bf16x8 __attribute__((ext_vector_type(8)));
typedef float f32x4 __attribute__((ext_vector_type(4)));
typedef unsigned short ushort8v __attribute__((ext_vector_type(8)));

__device__ __forceinline__ unsigned short f2bf(float f) {
  unsigned u = __builtin_bit_cast(unsigned, f);
  u += 0x7fffu + ((u >> 16) & 1u);     // RTNE
  return (unsigned short)(u >> 16);
}

__device__ __forceinline__ unsigned cvt2(float a, float b) {
  unsigned r;
  asm("v_cvt_pk_bf16_f32 %0, %1, %2" : "=v"(r) : "v"(a), "v"(b));
  return r;
}

__device__ __forceinline__ bf16x8 pack8(const f32x4 a, const f32x4 b) {
  union { uint4 u; bf16x8 v; } r;
  r.u.x = cvt2(a[0], a[1]); r.u.y = cvt2(a[2], a[3]);
  r.u.z = cvt2(b[0], b[1]); r.u.w = cvt2(b[2], b[3]);
  return r.v;
}

__device__ __forceinline__ void gload_lds16(const void* g, void* l) {
  __builtin_amdgcn_global_load_lds(
      (const __attribute__((address_space(1))) unsigned int*)g,
      (__attribute__((address_space(3))) unsigned int*)l, 16, 0, 0);
}

// ---- kernel 1: build W_ext pre-tiled for staging (round-12 layout) ----------
__global__ __launch_bounds__(256) void build_bext2(
    const float* __restrict__ w_b, const float* __restrict__ w_s,
    const float* __restrict__ c, unsigned short* __restrict__ bt) {
  const int gid = blockIdx.x * 256 + threadIdx.x;
  const int lane = gid & 63;
  const int q = (gid >> 6) & 3;
  const int wv = (gid >> 8) & 3;
  const int tile = gid >> 10;
  const int kt = tile % NTILES;
  const int cbq = tile / NTILES;
  const int a = kt / KB_TILES;
  const int ib = kt - a * KB_TILES;
  const int rg = lane >> 3, chh = lane & 7;
  const int o = cbq * 128 + wv * 32 + q * 8 + rg;
  const int i = ib * 64 + (chh ^ rg) * 8;

  float4 v0, v1;
  if (a < 8) {
    const float* cp = c + ((size_t)(a * OUTF + o)) * INF + i;
    const float* wp = w_s + (size_t)o * INF + i;
    const float4 c0 = *(const float4*)cp, c1 = *(const float4*)(cp + 4);
    const float4 s0 = *(const float4*)wp, s1 = *(const float4*)(wp + 4);
    v0 = make_float4(c0.x * s0.x, c0.y * s0.y, c0.z * s0.z, c0.w * s0.w);
    v1 = make_float4(c1.x * s1.x, c1.y * s1.y, c1.z * s1.z, c1.w * s1.w);
  } else {
    const float* bp = w_b + (size_t)o * INF + i;
    v0 = *(const float4*)bp;
    v1 = *(const float4*)(bp + 4);
  }
  ushort8v r;
  r[0] = f2bf(v0.x); r[1] = f2bf(v0.y); r[2] = f2bf(v0.z); r[3] = f2bf(v0.w);
  r[4] = f2bf(v1.x); r[5] = f2bf(v1.y); r[6] = f2bf(v1.z); r[7] = f2bf(v1.w);
  *(ushort8v*)(bt + (size_t)gid * 8) = r;
}

// ---- kernel 2: round-12 structure (proven 222us: 32-row waves, BK=64, ring-3,
//      9-unroll, A-fragment pipeline) + SPLIT-K=2: grid 1536 = 3 EXACT
//      generations at 2 blocks/CU (was 768 = 1.5 gens, 25% capacity idle).
//      K-halves combine via f32 atomicAdd into zeroed out (2-way commutative
//      => deterministic). --------------------------------------------------
__global__ __launch_bounds__(256, 2) void kan_gemm11(
    const float* __restrict__ x, const unsigned short* __restrict__ bt,
    float* __restrict__ out) {
  __shared__ unsigned short Bs[3][BN * BK];   // 3 x 16 KiB ring

  const int orig = blockIdx.x;
  const int bid = (orig & 7) * 192 + (orig >> 3);  // bijective XCD swizzle (1536=8*192)
  const int kh = bid / 768;                        // K-half: ib in [kh*6, kh*6+6)
  const int rem = bid - kh * 768;
  const int cb = rem / (BATCH / BM);               // cb-major within XCD chunk
  const int rb = rem - cb * (BATCH / BM);
  const int row0 = rb * BM, col0 = cb * BN;
  const int ib0 = kh * KH_IBS;

  const int t = threadIdx.x;
  const int lane = t & 63;
  const int w = t >> 6;                            // wave w: rows w*32..+31, all 128 cols
  const int lrow = lane & 15, lhi = lane >> 4;

  f32x4 acc[2][8];
#pragma unroll
  for (int mt = 0; mt < 2; ++mt)
#pragma unroll
    for (int n = 0; n < 8; ++n)
      acc[mt][n] = (f32x4){0.f, 0.f, 0.f, 0.f};

  const unsigned short* gt =
      bt + (size_t)cb * NTILES * TILE_SH + w * 2048 + lane * 8;
  const float* xb = x + (size_t)(row0 + w * 32 + lrow) * INF;

  const int c0 = lhi ^ (lrow & 7);
  const int c1 = (4 + lhi) ^ (lrow & 7);
  const unsigned short* pB0 = &Bs[0][lrow * 64 + c0 * 8];
  const unsigned short* pB1 = &Bs[0][lrow * 64 + c1 * 8];

  f32x4 ph[2][2][2], gg[2][2][2];   // [mt][kk][half] recurrence state
  bf16x8 afc[2][2];                 // [kk][mt] A-fragments for the CURRENT iter

  auto stage = [&](const unsigned short* src, int slot) {
#pragma unroll
    for (int q = 0; q < 4; ++q)
      gload_lds16(src + q * 512, &Bs[slot][w * 2048 + q * 512]);
  };

  auto mma_kk = [&](int kk, int slot) {
    const unsigned short* pB = kk ? pB1 : pB0;
#pragma unroll
    for (int n = 0; n < 8; ++n) {
      const bf16x8 b = *(const bf16x8*)(pB + slot * TILE_SH + n * 1024);
      acc[0][n] = __builtin_amdgcn_mfma_f32_16x16x32_bf16(afc[kk][0], b, acc[0][n], 0, 0, 0);
      acc[1][n] = __builtin_amdgcn_mfma_f32_16x16x32_bf16(afc[kk][1], b, acc[1][n], 0, 0, 0);
    }
  };

  f32x4 xr[2][2][2];   // [mt][kk][half]
  auto load_x = [&](int ib) {
#pragma unroll
    for (int mt = 0; mt < 2; ++mt)
#pragma unroll
      for (int kk = 0; kk < 2; ++kk) {
        const float* p = xb + ib * BK + mt * 16 * INF + kk * 32 + lhi * 8;
        xr[mt][kk][0] = *(const f32x4*)p;
        xr[mt][kk][1] = *(const f32x4*)(p + 4);
      }
  };
  auto silu_init = [&]() {
#pragma unroll
    for (int kk = 0; kk < 2; ++kk)
#pragma unroll
      for (int mt = 0; mt < 2; ++mt) {
        const f32x4 x0 = xr[mt][kk][0], x1 = xr[mt][kk][1];
        f32x4 s0, s1;
#pragma unroll
        for (int e = 0; e < 4; ++e) {
          s0[e] = x0[e] * __builtin_amdgcn_rcpf(
                      1.f + __builtin_amdgcn_exp2f(x0[e] * (-LOG2E)));
          s1[e] = x1[e] * __builtin_amdgcn_rcpf(
                      1.f + __builtin_amdgcn_exp2f(x1[e] * (-LOG2E)));
        }
        afc[kk][mt] = pack8(s0, s1);
        const f32x4 z0 = x0 * 1.75f + 3.5f;   // (x - g0)/h
        const f32x4 z1 = x1 * 1.75f + 3.5f;
#pragma unroll
        for (int e = 0; e < 4; ++e) {
          ph[mt][kk][0][e] = __builtin_amdgcn_exp2f(-(z0[e] * z0[e]) * LOG2E);
          ph[mt][kk][1][e] = __builtin_amdgcn_exp2f(-(z1[e] * z1[e]) * LOG2E);
          gg[mt][kk][0][e] = __builtin_amdgcn_exp2f(z0[e] * (2.f * LOG2E) - LOG2E);
          gg[mt][kk][1][e] = __builtin_amdgcn_exp2f(z1[e] * (2.f * LOG2E) - LOG2E);
        }
      }
  };
  auto pack_advance = [&]() {
#pragma unroll
    for (int kk = 0; kk < 2; ++kk)
#pragma unroll
      for (int mt = 0; mt < 2; ++mt) {
        afc[kk][mt] = pack8(ph[mt][kk][0], ph[mt][kk][1]);
        ph[mt][kk][0] *= gg[mt][kk][0];   // phi_{a+1} = phi_a * G_a
        ph[mt][kk][1] *= gg[mt][kk][1];
        gg[mt][kk][0] = gg[mt][kk][0] * EXPM2;
        gg[mt][kk][1] = gg[mt][kk][1] * EXPM2;
      }
  };

  // ---- prologue for this K-half ----
  load_x(ib0);
  const unsigned short* gib = gt + (size_t)ib0 * IB_SH;
  stage(gib + 8 * SLAB_SH, 0);   // (ib0, idx0 = slab8/silu)
  stage(gib, 1);                 // (ib0, idx1 = slab0)
  silu_init();
  asm volatile("s_waitcnt vmcnt(4)" ::: "memory");
  __builtin_amdgcn_s_barrier();
  __builtin_amdgcn_sched_barrier(0);

#pragma clang loop unroll(disable)
  for (int ib = ib0; ib < ib0 + KH_IBS; ++ib) {
    const bool last = (ib == ib0 + KH_IBS - 1);
#pragma unroll
    for (int j = 0; j < 9; ++j) {        // iter j consumes idx j (slab j?j-1:8)
      const int slot = j % 3;

      // A) x loads for next ib's silu (before the stage: drained at E)
      if (j == 8 && !last) load_x(ib + 1);

      // B) issue stage idx j+2
      if (j <= 6) {
        stage(gib + (j + 1) * SLAB_SH, (j + 2) % 3);       // (ib, idx j+2)
      } else if (!last) {
        if (j == 7) stage(gib + 8 * SLAB_SH + IB_SH, 0);   // (ib+1, idx0)
        else        stage(gib + IB_SH, 1);                 // (ib+1, idx1)
      }

      // C) MFMAs with the pipelined fragments (no VALU dependency)
      mma_kk(0, slot);
      mma_kk(1, slot);

      // D) build afc for the NEXT iteration (overlaps C on the VALU pipe)
      if (j < 8)       pack_advance();
      else if (!last)  silu_init();

      // E) counted wait: own stage(j+1) complete (FIFO); never 0 mid-loop
      if (!last || j < 7) {
        asm volatile("s_waitcnt vmcnt(4)" ::: "memory");
      } else if (j == 7) {
        asm volatile("s_waitcnt vmcnt(0)" ::: "memory");
      }
      if (!(last && j == 8)) {
        __builtin_amdgcn_s_barrier();
        __builtin_amdgcn_sched_barrier(0);
      }
    }
    gib += IB_SH;
  }

  // epilogue: combine K-halves; C/D layout col=lane&15, row=(lane>>4)*4+r
#pragma unroll
  for (int mt = 0; mt < 2; ++mt) {
#pragma unroll
    for (int n = 0; n < 8; ++n) {
      const int row = row0 + w * 32 + mt * 16 + lhi * 4;
      const int col = col0 + n * 16 + lrow;
#pragma unroll
      for (int r = 0; r < 4; ++r)
        atomicAdd(&out[(size_t)(row + r) * OUTF + col], acc[mt][n][r]);
    }
  }
}

// ---------------- fallback if ws too small (round-1 kernel) ------------------
__device__ __forceinline__ float phi_f(float x, float g) {
  float z = (x - g) * 1.75f;
  return __expf(-z * z);
}
__device__ __forceinline__ float silu_f(float x) {
  return x / (1.f + __expf(-x));
}

__global__ __launch_bounds__(256, 2) void kan_gemm_fb(
    const float* __restrict__ x, const float* __restrict__ w_b,
    const float* __restrict__ w_s, const float* __restrict__ c,
    float* __restrict__ out) {
  __shared__ unsigned short As[128][72];
  __shared__ unsigned short Bs[128][72];

  const int bid = blockIdx.x;
  const int cbf = bid % (OUTF / 128);
  const int rbf = bid / (OUTF / 128);
  const int row0 = rbf * 128, col0 = cbf * 128;

  const int t = threadIdx.x;
  const int lane = t & 63;
  const int w = t >> 6;
  const int wr = w >> 1, wc = w & 1;
  const int lrow = lane & 15, lhi = lane >> 4;

  f32x4 acc[4][4];
#pragma unroll
  for (int m = 0; m < 4; ++m)
#pragma unroll
    for (int n = 0; n < 4; ++n)
      acc[m][n] = (f32x4){0.f, 0.f, 0.f, 0.f};

  const int rsub = t >> 4;
  const int k4 = t & 15;

  for (int kt = 0; kt < KTOT / 64; ++kt) {
    const int a = kt / (INF / 64);
    const int i0 = (kt % (INF / 64)) * 64;
    const float ga = -2.f + (float)a * (4.f / 7.f);

#pragma unroll
    for (int p = 0; p < 8; ++p) {
      const int r = p * 16 + rsub;
      const float4 xv = *(const float4*)(x + (size_t)(row0 + r) * INF + i0 + k4 * 4);
      ushort4 av;
      if (a < 8) {
        av.x = f2bf(phi_f(xv.x, ga)); av.y = f2bf(phi_f(xv.y, ga));
        av.z = f2bf(phi_f(xv.z, ga)); av.w = f2bf(phi_f(xv.w, ga));
      } else {
        av.x = f2bf(silu_f(xv.x)); av.y = f2bf(silu_f(xv.y));
        av.z = f2bf(silu_f(xv.z)); av.w = f2bf(silu_f(xv.w));
      }
      *(ushort4*)&As[r][k4 * 4] = av;

      ushort4 bv;
      if (a < 8) {
        const float4 cv = *(const float4*)(c + ((size_t)a * OUTF + col0 + r) * INF + i0 + k4 * 4);
        const float4 wv = *(const float4*)(w_s + (size_t)(col0 + r) * INF + i0 + k4 * 4);
        bv.x = f2bf(cv.x * wv.x); bv.y = f2bf(cv.y * wv.y);
        bv.z = f2bf(cv.z * wv.z); bv.w = f2bf(cv.w * wv.w);
      } else {
        const float4 bbv = *(const float4*)(w_b + (size_t)(col0 + r) * INF + i0 + k4 * 4);
        bv.x = f2bf(bbv.x); bv.y = f2bf(bbv.y);
        bv.z = f2bf(bbv.z); bv.w = f2bf(bbv.w);
      }
      *(ushort4*)&Bs[r][k4 * 4] = bv;
    }
    __syncthreads();

#pragma unroll
    for (int kk = 0; kk < 2; ++kk) {
      bf16x8 af[4], bfr[4];
#pragma unroll
      for (int m = 0; m < 4; ++m)
        af[m] = *(const bf16x8*)&As[wr * 64 + m * 16 + lrow][kk * 32 + lhi * 8];
#pragma unroll
      for (int n = 0; n < 4; ++n)
        bfr[n] = *(const bf16x8*)&Bs[wc * 64 + n * 16 + lrow][kk * 32 + lhi * 8];
#pragma unroll
      for (int m = 0; m < 4; ++m)
#pragma unroll
        for (int n = 0; n < 4; ++n)
          acc[m][n] = __builtin_amdgcn_mfma_f32_16x16x32_bf16(af[m], bfr[n], acc[m][n], 0, 0, 0);
    }
    __syncthreads();
  }

#pragma unroll
  for (int m = 0; m < 4; ++m) {
#pragma unroll
    for (int n = 0; n < 4; ++n) {
      const int row = row0 + wr * 64 + m * 16 + lhi * 4;
      const int col = col0 + wc * 64 + n * 16 + lrow;
#pragma unroll
      for (int r = 0; r < 4; ++r)
        out[(size_t)(row + r) * OUTF + col] = acc[m][n][r];
    }
  }
}

extern "C" void kernel_launch(void* const* d_in, const int* in_sizes, int n_in,
                              void* d_out, int out_size, void* d_ws, size_t ws_size,
                              hipStream_t stream) {
  const float* x   = (const float*)d_in[0];
  const float* w_b = (const float*)d_in[1];
  const float* w_s = (const float*)d_in[2];
  const float* c   = (const float*)d_in[3];
  float* out = (float*)d_out;

  const size_t need = (size_t)OUTF * KTOT * sizeof(unsigned short);  // 10.1 MiB
  if (ws_size >= need) {
    unsigned short* bt = (unsigned short*)d_ws;
    hipMemsetAsync(out, 0, (size_t)out_size * sizeof(float), stream);
    build_bext2<<<(OUTF * KTOT / 8) / 256, 256, 0, stream>>>(w_b, w_s, c, bt);
    kan_gemm11<<<2 * (BATCH / BM) * (OUTF / BN), 256, 0, stream>>>(x, bt, out);
  } else {
    kan_gemm_fb<<<(BATCH / 128) * (OUTF / 128), 256, 0, stream>>>(x, w_b, w_s, c, out);
  }
}

// Round 16
// 204.865 us; speedup vs baseline: 1.3532x; 1.1411x over previous
//
#include <hip/hip_runtime.h>
#include <hip/hip_bf16.h>

#define BATCH 16384
#define INF 768
#define OUTF 768
#define NSLAB 9                  // slab order per ib: {8=silu, 0..7=rbf}
#define KTOT (NSLAB * INF)       // 6912
#define BM 128
#define BN 128
#define BK 64
#define KB_TILES 12              // INF / BK
#define NTILES (NSLAB * KB_TILES)

#define LOG2E 1.4426950408889634f
#define EXPM2 0.13533528323661270f   // exp(-2)

// tiled-B layout (shorts): tile(cb,kt) = 16 KB contiguous, kt = slab*12 + ib
#define TILE_SH 8192
#define IB_SH   8192             // ib stride within (cb): 1 tile
#define SLAB_SH (KB_TILES * TILE_SH)   // slab stride: 12 tiles

typedef __bf16 bf16x8 __attribute__((ext_vector_type(8)));
typedef float f32x4 __attribute__((ext_vector_type(4)));
typedef unsigned short ushort8v __attribute__((ext_vector_type(8)));

__device__ __forceinline__ unsigned short f2bf(float f) {
  unsigned u = __builtin_bit_cast(unsigned, f);
  u += 0x7fffu + ((u >> 16) & 1u);     // RTNE
  return (unsigned short)(u >> 16);
}

__device__ __forceinline__ unsigned cvt2(float a, float b) {
  unsigned r;
  asm("v_cvt_pk_bf16_f32 %0, %1, %2" : "=v"(r) : "v"(a), "v"(b));
  return r;
}

__device__ __forceinline__ bf16x8 pack8(const f32x4 a, const f32x4 b) {
  union { uint4 u; bf16x8 v; } r;
  r.u.x = cvt2(a[0], a[1]); r.u.y = cvt2(a[2], a[3]);
  r.u.z = cvt2(b[0], b[1]); r.u.w = cvt2(b[2], b[3]);
  return r.v;
}

__device__ __forceinline__ void gload_lds16(const void* g, void* l) {
  __builtin_amdgcn_global_load_lds(
      (const __attribute__((address_space(1))) unsigned int*)g,
      (__attribute__((address_space(3))) unsigned int*)l, 16, 0, 0);
}

// ---- kernel 1: build W_ext pre-tiled for staging (round-12 layout) ----------
__global__ __launch_bounds__(256) void build_bext2(
    const float* __restrict__ w_b, const float* __restrict__ w_s,
    const float* __restrict__ c, unsigned short* __restrict__ bt) {
  const int gid = blockIdx.x * 256 + threadIdx.x;
  const int lane = gid & 63;
  const int q = (gid >> 6) & 3;
  const int wv = (gid >> 8) & 3;
  const int tile = gid >> 10;
  const int kt = tile % NTILES;
  const int cbq = tile / NTILES;
  const int a = kt / KB_TILES;
  const int ib = kt - a * KB_TILES;
  const int rg = lane >> 3, chh = lane & 7;
  const int o = cbq * 128 + wv * 32 + q * 8 + rg;
  const int i = ib * 64 + (chh ^ rg) * 8;

  float4 v0, v1;
  if (a < 8) {
    const float* cp = c + ((size_t)(a * OUTF + o)) * INF + i;
    const float* wp = w_s + (size_t)o * INF + i;
    const float4 c0 = *(const float4*)cp, c1 = *(const float4*)(cp + 4);
    const float4 s0 = *(const float4*)wp, s1 = *(const float4*)(wp + 4);
    v0 = make_float4(c0.x * s0.x, c0.y * s0.y, c0.z * s0.z, c0.w * s0.w);
    v1 = make_float4(c1.x * s1.x, c1.y * s1.y, c1.z * s1.z, c1.w * s1.w);
  } else {
    const float* bp = w_b + (size_t)o * INF + i;
    v0 = *(const float4*)bp;
    v1 = *(const float4*)(bp + 4);
  }
  ushort8v r;
  r[0] = f2bf(v0.x); r[1] = f2bf(v0.y); r[2] = f2bf(v0.z); r[3] = f2bf(v0.w);
  r[4] = f2bf(v1.x); r[5] = f2bf(v1.y); r[6] = f2bf(v1.z); r[7] = f2bf(v1.w);
  *(ushort8v*)(bt + (size_t)gid * 8) = r;
}

// ---- kernel 2: EXACT round-12 structure (proven 202us, 3 blocks/CU
//      LDS-limited, one clean generation) + T5: s_setprio(1) around the MFMA
//      cluster. Phase roles per iter {stage-issue | MFMA | VALU-pack} + 3
//      co-resident blocks at different phases = the regime where setprio
//      pays (m218b/m224); zero correctness risk. -----------------------------
__global__ __launch_bounds__(256, 2) void kan_gemm13(
    const float* __restrict__ x, const unsigned short* __restrict__ bt,
    float* __restrict__ out) {
  __shared__ unsigned short Bs[3][BN * BK];   // 3 x 16 KiB ring

  const int orig = blockIdx.x;
  const int bid = (orig & 7) * 96 + (orig >> 3);   // bijective XCD swizzle (768=8*96)
  const int cb = bid / (BATCH / BM);               // cb-major: XCD chunk shares B-strip
  const int rb = bid - cb * (BATCH / BM);
  const int row0 = rb * BM, col0 = cb * BN;

  const int t = threadIdx.x;
  const int lane = t & 63;
  const int w = t >> 6;                            // wave w: rows w*32..+31, all 128 cols
  const int lrow = lane & 15, lhi = lane >> 4;

  f32x4 acc[2][8];
#pragma unroll
  for (int mt = 0; mt < 2; ++mt)
#pragma unroll
    for (int n = 0; n < 8; ++n)
      acc[mt][n] = (f32x4){0.f, 0.f, 0.f, 0.f};

  const unsigned short* gt =
      bt + (size_t)cb * NTILES * TILE_SH + w * 2048 + lane * 8;
  const float* xb = x + (size_t)(row0 + w * 32 + lrow) * INF;

  const int c0 = lhi ^ (lrow & 7);
  const int c1 = (4 + lhi) ^ (lrow & 7);
  const unsigned short* pB0 = &Bs[0][lrow * 64 + c0 * 8];
  const unsigned short* pB1 = &Bs[0][lrow * 64 + c1 * 8];

  f32x4 ph[2][2][2], gg[2][2][2];   // [mt][kk][half] recurrence state
  bf16x8 afc[2][2];                 // [kk][mt] A-fragments for the CURRENT iter

  auto stage = [&](const unsigned short* src, int slot) {
#pragma unroll
    for (int q = 0; q < 4; ++q)
      gload_lds16(src + q * 512, &Bs[slot][w * 2048 + q * 512]);
  };

  auto mma_kk = [&](int kk, int slot) {
    const unsigned short* pB = kk ? pB1 : pB0;
#pragma unroll
    for (int n = 0; n < 8; ++n) {
      const bf16x8 b = *(const bf16x8*)(pB + slot * TILE_SH + n * 1024);
      acc[0][n] = __builtin_amdgcn_mfma_f32_16x16x32_bf16(afc[kk][0], b, acc[0][n], 0, 0, 0);
      acc[1][n] = __builtin_amdgcn_mfma_f32_16x16x32_bf16(afc[kk][1], b, acc[1][n], 0, 0, 0);
    }
  };

  f32x4 xr[2][2][2];   // [mt][kk][half]
  auto load_x = [&](int ib) {
#pragma unroll
    for (int mt = 0; mt < 2; ++mt)
#pragma unroll
      for (int kk = 0; kk < 2; ++kk) {
        const float* p = xb + ib * BK + mt * 16 * INF + kk * 32 + lhi * 8;
        xr[mt][kk][0] = *(const f32x4*)p;
        xr[mt][kk][1] = *(const f32x4*)(p + 4);
      }
  };
  auto silu_init = [&]() {
#pragma unroll
    for (int kk = 0; kk < 2; ++kk)
#pragma unroll
      for (int mt = 0; mt < 2; ++mt) {
        const f32x4 x0 = xr[mt][kk][0], x1 = xr[mt][kk][1];
        f32x4 s0, s1;
#pragma unroll
        for (int e = 0; e < 4; ++e) {
          s0[e] = x0[e] * __builtin_amdgcn_rcpf(
                      1.f + __builtin_amdgcn_exp2f(x0[e] * (-LOG2E)));
          s1[e] = x1[e] * __builtin_amdgcn_rcpf(
                      1.f + __builtin_amdgcn_exp2f(x1[e] * (-LOG2E)));
        }
        afc[kk][mt] = pack8(s0, s1);
        const f32x4 z0 = x0 * 1.75f + 3.5f;   // (x - g0)/h
        const f32x4 z1 = x1 * 1.75f + 3.5f;
#pragma unroll
        for (int e = 0; e < 4; ++e) {
          ph[mt][kk][0][e] = __builtin_amdgcn_exp2f(-(z0[e] * z0[e]) * LOG2E);
          ph[mt][kk][1][e] = __builtin_amdgcn_exp2f(-(z1[e] * z1[e]) * LOG2E);
          gg[mt][kk][0][e] = __builtin_amdgcn_exp2f(z0[e] * (2.f * LOG2E) - LOG2E);
          gg[mt][kk][1][e] = __builtin_amdgcn_exp2f(z1[e] * (2.f * LOG2E) - LOG2E);
        }
      }
  };
  auto pack_advance = [&]() {
#pragma unroll
    for (int kk = 0; kk < 2; ++kk)
#pragma unroll
      for (int mt = 0; mt < 2; ++mt) {
        afc[kk][mt] = pack8(ph[mt][kk][0], ph[mt][kk][1]);
        ph[mt][kk][0] *= gg[mt][kk][0];   // phi_{a+1} = phi_a * G_a
        ph[mt][kk][1] *= gg[mt][kk][1];
        gg[mt][kk][0] = gg[mt][kk][0] * EXPM2;
        gg[mt][kk][1] = gg[mt][kk][1] * EXPM2;
      }
  };

  // ---- prologue: x(ib0) first (oldest in FIFO), stages idx0/idx1;
  //      silu_init auto-drains x; vmcnt(4) ensures stage idx0 complete. ------
  load_x(0);
  const unsigned short* gib = gt;
  stage(gib + 8 * SLAB_SH, 0);   // (ib0, idx0 = slab8/silu)
  stage(gib, 1);                 // (ib0, idx1 = slab0)
  silu_init();                   // afc = silu (consumed at iter j==0)
  asm volatile("s_waitcnt vmcnt(4)" ::: "memory");
  __builtin_amdgcn_s_barrier();
  __builtin_amdgcn_sched_barrier(0);

#pragma clang loop unroll(disable)
  for (int ib = 0; ib < KB_TILES; ++ib) {
    const bool last = (ib == KB_TILES - 1);
#pragma unroll
    for (int j = 0; j < 9; ++j) {        // iter j consumes idx j (slab j?j-1:8)
      const int slot = j % 3;

      // A) x loads for next ib's silu (issued BEFORE the stage so its
      //    auto-drain in (D) spares the newest prefetch)
      if (j == 8 && !last) load_x(ib + 1);

      // B) issue stage idx j+2
      if (j <= 6) {
        stage(gib + (j + 1) * SLAB_SH, (j + 2) % 3);       // (ib, idx j+2)
      } else if (!last) {
        if (j == 7) stage(gib + 8 * SLAB_SH + IB_SH, 0);   // (ib+1, idx0)
        else        stage(gib + IB_SH, 1);                 // (ib+1, idx1)
      }

      // C) MFMAs with the pipelined fragments — priority-boosted (T5)
      __builtin_amdgcn_s_setprio(1);
      mma_kk(0, slot);
      mma_kk(1, slot);
      __builtin_amdgcn_s_setprio(0);

      // D) build afc for the NEXT iteration (overlaps C on the VALU pipe)
      if (j < 8)       pack_advance();   // next iter consumes slab j
      else if (!last)  silu_init();      // next iter is (ib+1, silu)

      // E) counted wait + barrier
      if (!last || j < 7) {
        asm volatile("s_waitcnt vmcnt(4)" ::: "memory");
      } else if (j == 7) {
        asm volatile("s_waitcnt vmcnt(0)" ::: "memory");
      }
      if (!(last && j == 8)) {
        __builtin_amdgcn_s_barrier();
        __builtin_amdgcn_sched_barrier(0);   // no ds_read hoists above barrier
      }
    }
    gib += IB_SH;
  }

  // epilogue: C/D layout col=lane&15, row=(lane>>4)*4+r
#pragma unroll
  for (int mt = 0; mt < 2; ++mt) {
#pragma unroll
    for (int n = 0; n < 8; ++n) {
      const int row = row0 + w * 32 + mt * 16 + lhi * 4;
      const int col = col0 + n * 16 + lrow;
#pragma unroll
      for (int r = 0; r < 4; ++r)
        out[(size_t)(row + r) * OUTF + col] = acc[mt][n][r];
    }
  }
}

// ---------------- fallback if ws too small (round-1 kernel) ------------------
__device__ __forceinline__ float phi_f(float x, float g) {
  float z = (x - g) * 1.75f;
  return __expf(-z * z);
}
__device__ __forceinline__ float silu_f(float x) {
  return x / (1.f + __expf(-x));
}

__global__ __launch_bounds__(256, 2) void kan_gemm_fb(
    const float* __restrict__ x, const float* __restrict__ w_b,
    const float* __restrict__ w_s, const float* __restrict__ c,
    float* __restrict__ out) {
  __shared__ unsigned short As[128][72];
  __shared__ unsigned short Bs[128][72];

  const int bid = blockIdx.x;
  const int cbf = bid % (OUTF / 128);
  const int rbf = bid / (OUTF / 128);
  const int row0 = rbf * 128, col0 = cbf * 128;

  const int t = threadIdx.x;
  const int lane = t & 63;
  const int w = t >> 6;
  const int wr = w >> 1, wc = w & 1;
  const int lrow = lane & 15, lhi = lane >> 4;

  f32x4 acc[4][4];
#pragma unroll
  for (int m = 0; m < 4; ++m)
#pragma unroll
    for (int n = 0; n < 4; ++n)
      acc[m][n] = (f32x4){0.f, 0.f, 0.f, 0.f};

  const int rsub = t >> 4;
  const int k4 = t & 15;

  for (int kt = 0; kt < KTOT / 64; ++kt) {
    const int a = kt / (INF / 64);
    const int i0 = (kt % (INF / 64)) * 64;
    const float ga = -2.f + (float)a * (4.f / 7.f);

#pragma unroll
    for (int p = 0; p < 8; ++p) {
      const int r = p * 16 + rsub;
      const float4 xv = *(const float4*)(x + (size_t)(row0 + r) * INF + i0 + k4 * 4);
      ushort4 av;
      if (a < 8) {
        av.x = f2bf(phi_f(xv.x, ga)); av.y = f2bf(phi_f(xv.y, ga));
        av.z = f2bf(phi_f(xv.z, ga)); av.w = f2bf(phi_f(xv.w, ga));
      } else {
        av.x = f2bf(silu_f(xv.x)); av.y = f2bf(silu_f(xv.y));
        av.z = f2bf(silu_f(xv.z)); av.w = f2bf(silu_f(xv.w));
      }
      *(ushort4*)&As[r][k4 * 4] = av;

      ushort4 bv;
      if (a < 8) {
        const float4 cv = *(const float4*)(c + ((size_t)a * OUTF + col0 + r) * INF + i0 + k4 * 4);
        const float4 wv = *(const float4*)(w_s + (size_t)(col0 + r) * INF + i0 + k4 * 4);
        bv.x = f2bf(cv.x * wv.x); bv.y = f2bf(cv.y * wv.y);
        bv.z = f2bf(cv.z * wv.z); bv.w = f2bf(cv.w * wv.w);
      } else {
        const float4 bbv = *(const float4*)(w_b + (size_t)(col0 + r) * INF + i0 + k4 * 4);
        bv.x = f2bf(bbv.x); bv.y = f2bf(bbv.y);
        bv.z = f2bf(bbv.z); bv.w = f2bf(bbv.w);
      }
      *(ushort4*)&Bs[r][k4 * 4] = bv;
    }
    __syncthreads();

#pragma unroll
    for (int kk = 0; kk < 2; ++kk) {
      bf16x8 af[4], bfr[4];
#pragma unroll
      for (int m = 0; m < 4; ++m)
        af[m] = *(const bf16x8*)&As[wr * 64 + m * 16 + lrow][kk * 32 + lhi * 8];
#pragma unroll
      for (int n = 0; n < 4; ++n)
        bfr[n] = *(const bf16x8*)&Bs[wc * 64 + n * 16 + lrow][kk * 32 + lhi * 8];
#pragma unroll
      for (int m = 0; m < 4; ++m)
#pragma unroll
        for (int n = 0; n < 4; ++n)
          acc[m][n] = __builtin_amdgcn_mfma_f32_16x16x32_bf16(af[m], bfr[n], acc[m][n], 0, 0, 0);
    }
    __syncthreads();
  }

#pragma unroll
  for (int m = 0; m < 4; ++m) {
#pragma unroll
    for (int n = 0; n < 4; ++n) {
      const int row = row0 + wr * 64 + m * 16 + lhi * 4;
      const int col = col0 + wc * 64 + n * 16 + lrow;
#pragma unroll
      for (int r = 0; r < 4; ++r)
        out[(size_t)(row + r) * OUTF + col] = acc[m][n][r];
    }
  }
}

extern "C" void kernel_launch(void* const* d_in, const int* in_sizes, int n_in,
                              void* d_out, int out_size, void* d_ws, size_t ws_size,
                              hipStream_t stream) {
  const float* x   = (const float*)d_in[0];
  const float* w_b = (const float*)d_in[1];
  const float* w_s = (const float*)d_in[2];
  const float* c   = (const float*)d_in[3];
  float* out = (float*)d_out;

  const size_t need = (size_t)OUTF * KTOT * sizeof(unsigned short);  // 10.1 MiB
  if (ws_size >= need) {
    unsigned short* bt = (unsigned short*)d_ws;
    build_bext2<<<(OUTF * KTOT / 8) / 256, 256, 0, stream>>>(w_b, w_s, c, bt);
    kan_gemm13<<<(BATCH / BM) * (OUTF / BN), 256, 0, stream>>>(x, bt, out);
  } else {
    kan_gemm_fb<<<(BATCH / 128) * (OUTF / 128), 256, 0, stream>>>(x, w_b, w_s, c, out);
  }
}

// Round 18
// 201.779 us; speedup vs baseline: 1.3739x; 1.0153x over previous
//
#include <hip/hip_runtime.h>
#include <hip/hip_bf16.h>

#define BATCH 16384
#define INF 768
#define OUTF 768
#define NSLAB 9                  // slab order per ib: {8=silu, 0..7=rbf}
#define KTOT (NSLAB * INF)       // 6912
#define BM 128
#define BN 128
#define BK 64
#define KB_TILES 12              // INF / BK
#define NTILES (NSLAB * KB_TILES)

#define LOG2E 1.4426950408889634f
#define EXPM2 0.13533528323661270f   // exp(-2)

// tiled-B layout (shorts): tile(cb,kt) = 16 KB contiguous, kt = slab*12 + ib
#define TILE_SH 8192
#define IB_SH   8192             // ib stride within (cb): 1 tile
#define SLAB_SH (KB_TILES * TILE_SH)   // slab stride: 12 tiles

typedef __bf16 bf16x8 __attribute__((ext_vector_type(8)));
typedef float f32x4 __attribute__((ext_vector_type(4)));
typedef unsigned short ushort8v __attribute__((ext_vector_type(8)));

__device__ __forceinline__ unsigned short f2bf(float f) {
  unsigned u = __builtin_bit_cast(unsigned, f);
  u += 0x7fffu + ((u >> 16) & 1u);     // RTNE
  return (unsigned short)(u >> 16);
}

__device__ __forceinline__ unsigned cvt2(float a, float b) {
  unsigned r;
  asm("v_cvt_pk_bf16_f32 %0, %1, %2" : "=v"(r) : "v"(a), "v"(b));
  return r;
}

__device__ __forceinline__ bf16x8 pack8(const f32x4 a, const f32x4 b) {
  union { uint4 u; bf16x8 v; } r;
  r.u.x = cvt2(a[0], a[1]); r.u.y = cvt2(a[2], a[3]);
  r.u.z = cvt2(b[0], b[1]); r.u.w = cvt2(b[2], b[3]);
  return r.v;
}

__device__ __forceinline__ void gload_lds16(const void* g, void* l) {
  __builtin_amdgcn_global_load_lds(
      (const __attribute__((address_space(1))) unsigned int*)g,
      (__attribute__((address_space(3))) unsigned int*)l, 16, 0, 0);
}

// ---- kernel 1: build W_ext pre-tiled for staging (round-12 layout) ----------
__global__ __launch_bounds__(256) void build_bext2(
    const float* __restrict__ w_b, const float* __restrict__ w_s,
    const float* __restrict__ c, unsigned short* __restrict__ bt) {
  const int gid = blockIdx.x * 256 + threadIdx.x;
  const int lane = gid & 63;
  const int q = (gid >> 6) & 3;
  const int wv = (gid >> 8) & 3;
  const int tile = gid >> 10;
  const int kt = tile % NTILES;
  const int cbq = tile / NTILES;
  const int a = kt / KB_TILES;
  const int ib = kt - a * KB_TILES;
  const int rg = lane >> 3, chh = lane & 7;
  const int o = cbq * 128 + wv * 32 + q * 8 + rg;
  const int i = ib * 64 + (chh ^ rg) * 8;

  float4 v0, v1;
  if (a < 8) {
    const float* cp = c + ((size_t)(a * OUTF + o)) * INF + i;
    const float* wp = w_s + (size_t)o * INF + i;
    const float4 c0 = *(const float4*)cp, c1 = *(const float4*)(cp + 4);
    const float4 s0 = *(const float4*)wp, s1 = *(const float4*)(wp + 4);
    v0 = make_float4(c0.x * s0.x, c0.y * s0.y, c0.z * s0.z, c0.w * s0.w);
    v1 = make_float4(c1.x * s1.x, c1.y * s1.y, c1.z * s1.z, c1.w * s1.w);
  } else {
    const float* bp = w_b + (size_t)o * INF + i;
    v0 = *(const float4*)bp;
    v1 = *(const float4*)(bp + 4);
  }
  ushort8v r;
  r[0] = f2bf(v0.x); r[1] = f2bf(v0.y); r[2] = f2bf(v0.z); r[3] = f2bf(v0.w);
  r[4] = f2bf(v1.x); r[5] = f2bf(v1.y); r[6] = f2bf(v1.z); r[7] = f2bf(v1.w);
  *(ushort8v*)(bt + (size_t)gid * 8) = r;
}

// ---- kernel 2: CHAMPION (round 12, 202us bench). 32-row waves, BK=64,
//      ring-3 LDS + counted vmcnt(4) (never 0 mid-loop), 9-slab unroll with
//      compile-time slots, A entirely in registers via phi-recurrence, and
//      the A-fragment software pipeline (afc built one iter ahead, overlapping
//      MFMA on the VALU pipe). Register state 128 VGPR + 64 acc = 192/wave
//      (2 waves/SIMD). Measured: MfmaUtil 35%, VALU 39%, conflicts 0, no
//      spill. Closed levers (all measured negative or correctness-failed):
//      LB(256,3)/BN192/64x64-waves (spill), split-K (atomics+prologue cost),
//      setprio (-1%), z-direct state cut (quarantined: 2 unexplained fails).
__global__ __launch_bounds__(256, 2) void kan_gemm9(
    const float* __restrict__ x, const unsigned short* __restrict__ bt,
    float* __restrict__ out) {
  __shared__ unsigned short Bs[3][BN * BK];   // 3 x 16 KiB ring

  const int orig = blockIdx.x;
  const int bid = (orig & 7) * 96 + (orig >> 3);   // bijective XCD swizzle (768=8*96)
  const int cb = bid / (BATCH / BM);               // cb-major: XCD chunk shares B-strip
  const int rb = bid - cb * (BATCH / BM);
  const int row0 = rb * BM, col0 = cb * BN;

  const int t = threadIdx.x;
  const int lane = t & 63;
  const int w = t >> 6;                            // wave w: rows w*32..+31, all 128 cols
  const int lrow = lane & 15, lhi = lane >> 4;

  f32x4 acc[2][8];
#pragma unroll
  for (int mt = 0; mt < 2; ++mt)
#pragma unroll
    for (int n = 0; n < 8; ++n)
      acc[mt][n] = (f32x4){0.f, 0.f, 0.f, 0.f};

  const unsigned short* gt =
      bt + (size_t)cb * NTILES * TILE_SH + w * 2048 + lane * 8;
  const float* xb = x + (size_t)(row0 + w * 32 + lrow) * INF;

  const int c0 = lhi ^ (lrow & 7);
  const int c1 = (4 + lhi) ^ (lrow & 7);
  const unsigned short* pB0 = &Bs[0][lrow * 64 + c0 * 8];
  const unsigned short* pB1 = &Bs[0][lrow * 64 + c1 * 8];

  f32x4 ph[2][2][2], gg[2][2][2];   // [mt][kk][half] recurrence state
  bf16x8 afc[2][2];                 // [kk][mt] A-fragments for the CURRENT iter

  auto stage = [&](const unsigned short* src, int slot) {
#pragma unroll
    for (int q = 0; q < 4; ++q)
      gload_lds16(src + q * 512, &Bs[slot][w * 2048 + q * 512]);
  };

  auto mma_kk = [&](int kk, int slot) {
    const unsigned short* pB = kk ? pB1 : pB0;
#pragma unroll
    for (int n = 0; n < 8; ++n) {
      const bf16x8 b = *(const bf16x8*)(pB + slot * TILE_SH + n * 1024);
      acc[0][n] = __builtin_amdgcn_mfma_f32_16x16x32_bf16(afc[kk][0], b, acc[0][n], 0, 0, 0);
      acc[1][n] = __builtin_amdgcn_mfma_f32_16x16x32_bf16(afc[kk][1], b, acc[1][n], 0, 0, 0);
    }
  };

  f32x4 xr[2][2][2];   // [mt][kk][half]
  auto load_x = [&](int ib) {
#pragma unroll
    for (int mt = 0; mt < 2; ++mt)
#pragma unroll
      for (int kk = 0; kk < 2; ++kk) {
        const float* p = xb + ib * BK + mt * 16 * INF + kk * 32 + lhi * 8;
        xr[mt][kk][0] = *(const f32x4*)p;
        xr[mt][kk][1] = *(const f32x4*)(p + 4);
      }
  };
  auto silu_init = [&]() {
#pragma unroll
    for (int kk = 0; kk < 2; ++kk)
#pragma unroll
      for (int mt = 0; mt < 2; ++mt) {
        const f32x4 x0 = xr[mt][kk][0], x1 = xr[mt][kk][1];
        f32x4 s0, s1;
#pragma unroll
        for (int e = 0; e < 4; ++e) {
          s0[e] = x0[e] * __builtin_amdgcn_rcpf(
                      1.f + __builtin_amdgcn_exp2f(x0[e] * (-LOG2E)));
          s1[e] = x1[e] * __builtin_amdgcn_rcpf(
                      1.f + __builtin_amdgcn_exp2f(x1[e] * (-LOG2E)));
        }
        afc[kk][mt] = pack8(s0, s1);
        const f32x4 z0 = x0 * 1.75f + 3.5f;   // (x - g0)/h
        const f32x4 z1 = x1 * 1.75f + 3.5f;
#pragma unroll
        for (int e = 0; e < 4; ++e) {
          ph[mt][kk][0][e] = __builtin_amdgcn_exp2f(-(z0[e] * z0[e]) * LOG2E);
          ph[mt][kk][1][e] = __builtin_amdgcn_exp2f(-(z1[e] * z1[e]) * LOG2E);
          gg[mt][kk][0][e] = __builtin_amdgcn_exp2f(z0[e] * (2.f * LOG2E) - LOG2E);
          gg[mt][kk][1][e] = __builtin_amdgcn_exp2f(z1[e] * (2.f * LOG2E) - LOG2E);
        }
      }
  };
  auto pack_advance = [&]() {
#pragma unroll
    for (int kk = 0; kk < 2; ++kk)
#pragma unroll
      for (int mt = 0; mt < 2; ++mt) {
        afc[kk][mt] = pack8(ph[mt][kk][0], ph[mt][kk][1]);
        ph[mt][kk][0] *= gg[mt][kk][0];   // phi_{a+1} = phi_a * G_a
        ph[mt][kk][1] *= gg[mt][kk][1];
        gg[mt][kk][0] = gg[mt][kk][0] * EXPM2;
        gg[mt][kk][1] = gg[mt][kk][1] * EXPM2;
      }
  };

  // ---- prologue: x(ib0) first (oldest in FIFO), stages idx0/idx1;
  //      silu_init auto-drains x; vmcnt(4) ensures stage idx0 complete. ------
  load_x(0);
  const unsigned short* gib = gt;
  stage(gib + 8 * SLAB_SH, 0);   // (ib0, idx0 = slab8/silu)
  stage(gib, 1);                 // (ib0, idx1 = slab0)
  silu_init();                   // afc = silu (consumed at iter j==0)
  asm volatile("s_waitcnt vmcnt(4)" ::: "memory");
  __builtin_amdgcn_s_barrier();
  __builtin_amdgcn_sched_barrier(0);

#pragma clang loop unroll(disable)
  for (int ib = 0; ib < KB_TILES; ++ib) {
    const bool last = (ib == KB_TILES - 1);
#pragma unroll
    for (int j = 0; j < 9; ++j) {        // iter j consumes idx j (slab j?j-1:8)
      const int slot = j % 3;

      // A) x loads for next ib's silu (issued BEFORE the stage so its
      //    auto-drain in (D) spares the newest prefetch)
      if (j == 8 && !last) load_x(ib + 1);

      // B) issue stage idx j+2
      if (j <= 6) {
        stage(gib + (j + 1) * SLAB_SH, (j + 2) % 3);       // (ib, idx j+2)
      } else if (!last) {
        if (j == 7) stage(gib + 8 * SLAB_SH + IB_SH, 0);   // (ib+1, idx0)
        else        stage(gib + IB_SH, 1);                 // (ib+1, idx1)
      }

      // C) MFMAs with the pipelined fragments (no VALU dependency)
      mma_kk(0, slot);
      mma_kk(1, slot);

      // D) build afc for the NEXT iteration (overlaps C on the VALU pipe)
      if (j < 8)       pack_advance();   // next iter consumes slab j
      else if (!last)  silu_init();      // next iter is (ib+1, silu)

      // E) counted wait + barrier
      if (!last || j < 7) {
        asm volatile("s_waitcnt vmcnt(4)" ::: "memory");
      } else if (j == 7) {
        asm volatile("s_waitcnt vmcnt(0)" ::: "memory");
      }
      if (!(last && j == 8)) {
        __builtin_amdgcn_s_barrier();
        __builtin_amdgcn_sched_barrier(0);   // no ds_read hoists above barrier
      }
    }
    gib += IB_SH;
  }

  // epilogue: C/D layout col=lane&15, row=(lane>>4)*4+r
#pragma unroll
  for (int mt = 0; mt < 2; ++mt) {
#pragma unroll
    for (int n = 0; n < 8; ++n) {
      const int row = row0 + w * 32 + mt * 16 + lhi * 4;
      const int col = col0 + n * 16 + lrow;
#pragma unroll
      for (int r = 0; r < 4; ++r)
        out[(size_t)(row + r) * OUTF + col] = acc[mt][n][r];
    }
  }
}

// ---------------- fallback if ws too small (round-1 kernel) ------------------
__device__ __forceinline__ float phi_f(float x, float g) {
  float z = (x - g) * 1.75f;
  return __expf(-z * z);
}
__device__ __forceinline__ float silu_f(float x) {
  return x / (1.f + __expf(-x));
}

__global__ __launch_bounds__(256, 2) void kan_gemm_fb(
    const float* __restrict__ x, const float* __restrict__ w_b,
    const float* __restrict__ w_s, const float* __restrict__ c,
    float* __restrict__ out) {
  __shared__ unsigned short As[128][72];
  __shared__ unsigned short Bs[128][72];

  const int bid = blockIdx.x;
  const int cbf = bid % (OUTF / 128);
  const int rbf = bid / (OUTF / 128);
  const int row0 = rbf * 128, col0 = cbf * 128;

  const int t = threadIdx.x;
  const int lane = t & 63;
  const int w = t >> 6;
  const int wr = w >> 1, wc = w & 1;
  const int lrow = lane & 15, lhi = lane >> 4;

  f32x4 acc[4][4];
#pragma unroll
  for (int m = 0; m < 4; ++m)
#pragma unroll
    for (int n = 0; n < 4; ++n)
      acc[m][n] = (f32x4){0.f, 0.f, 0.f, 0.f};

  const int rsub = t >> 4;
  const int k4 = t & 15;

  for (int kt = 0; kt < KTOT / 64; ++kt) {
    const int a = kt / (INF / 64);
    const int i0 = (kt % (INF / 64)) * 64;
    const float ga = -2.f + (float)a * (4.f / 7.f);

#pragma unroll
    for (int p = 0; p < 8; ++p) {
      const int r = p * 16 + rsub;
      const float4 xv = *(const float4*)(x + (size_t)(row0 + r) * INF + i0 + k4 * 4);
      ushort4 av;
      if (a < 8) {
        av.x = f2bf(phi_f(xv.x, ga)); av.y = f2bf(phi_f(xv.y, ga));
        av.z = f2bf(phi_f(xv.z, ga)); av.w = f2bf(phi_f(xv.w, ga));
      } else {
        av.x = f2bf(silu_f(xv.x)); av.y = f2bf(silu_f(xv.y));
        av.z = f2bf(silu_f(xv.z)); av.w = f2bf(silu_f(xv.w));
      }
      *(ushort4*)&As[r][k4 * 4] = av;

      ushort4 bv;
      if (a < 8) {
        const float4 cv = *(const float4*)(c + ((size_t)a * OUTF + col0 + r) * INF + i0 + k4 * 4);
        const float4 wv = *(const float4*)(w_s + (size_t)(col0 + r) * INF + i0 + k4 * 4);
        bv.x = f2bf(cv.x * wv.x); bv.y = f2bf(cv.y * wv.y);
        bv.z = f2bf(cv.z * wv.z); bv.w = f2bf(cv.w * wv.w);
      } else {
        const float4 bbv = *(const float4*)(w_b + (size_t)(col0 + r) * INF + i0 + k4 * 4);
        bv.x = f2bf(bbv.x); bv.y = f2bf(bbv.y);
        bv.z = f2bf(bbv.z); bv.w = f2bf(bbv.w);
      }
      *(ushort4*)&Bs[r][k4 * 4] = bv;
    }
    __syncthreads();

#pragma unroll
    for (int kk = 0; kk < 2; ++kk) {
      bf16x8 af[4], bfr[4];
#pragma unroll
      for (int m = 0; m < 4; ++m)
        af[m] = *(const bf16x8*)&As[wr * 64 + m * 16 + lrow][kk * 32 + lhi * 8];
#pragma unroll
      for (int n = 0; n < 4; ++n)
        bfr[n] = *(const bf16x8*)&Bs[wc * 64 + n * 16 + lrow][kk * 32 + lhi * 8];
#pragma unroll
      for (int m = 0; m < 4; ++m)
#pragma unroll
        for (int n = 0; n < 4; ++n)
          acc[m][n] = __builtin_amdgcn_mfma_f32_16x16x32_bf16(af[m], bfr[n], acc[m][n], 0, 0, 0);
    }
    __syncthreads();
  }

#pragma unroll
  for (int m = 0; m < 4; ++m) {
#pragma unroll
    for (int n = 0; n < 4; ++n) {
      const int row = row0 + wr * 64 + m * 16 + lhi * 4;
      const int col = col0 + wc * 64 + n * 16 + lrow;
#pragma unroll
      for (int r = 0; r < 4; ++r)
        out[(size_t)(row + r) * OUTF + col] = acc[m][n][r];
    }
  }
}

extern "C" void kernel_launch(void* const* d_in, const int* in_sizes, int n_in,
                              void* d_out, int out_size, void* d_ws, size_t ws_size,
                              hipStream_t stream) {
  const float* x   = (const float*)d_in[0];
  const float* w_b = (const float*)d_in[1];
  const float* w_s = (const float*)d_in[2];
  const float* c   = (const float*)d_in[3];
  float* out = (float*)d_out;

  const size_t need = (size_t)OUTF * KTOT * sizeof(unsigned short);  // 10.1 MiB
  if (ws_size >= need) {
    unsigned short* bt = (unsigned short*)d_ws;
    build_bext2<<<(OUTF * KTOT / 8) / 256, 256, 0, stream>>>(w_b, w_s, c, bt);
    kan_gemm9<<<(BATCH / BM) * (OUTF / BN), 256, 0, stream>>>(x, bt, out);
  } else {
    kan_gemm_fb<<<(BATCH / 128) * (OUTF / 128), 256, 0, stream>>>(x, w_b, w_s, c, out);
  }
}